// Round 4
// baseline (128.646 us; speedup 1.0000x reference)
//
#include <hip/hip_runtime.h>

// Multi-scale parabolic morphological closing, 2-dispatch fused pipeline.
// Algebra: dilations along different axes commute (max-plus), as do erosions:
//   closing = ev.eh.dv.dh = (eh.ev).(dh.dv)
//   K_dil: ws  = dh(dv(x))      (both max)
//   K_ero: out = eh(ev(ws))     (both min)
// weight(d) = c * (4/W^2) * d^2 — pow2 * small-int products are exact.
//
// R8 (from R7 post-mortem): dur 119.8 = fill(48.9, harness tax) + 2 x 35.5.
// Kernel is VALU-issue-bound while issuing (~21us busy = model's 2-op/tap
// floor + aux), ~40% residual is barrier drain + load latency. Fixes:
//  (a) tap PAIRING: acc = op(acc, op(c1,c2)) fuses to v_max3/v_min3 ->
//      3 VALU per 2 taps (-25% tap work). Max/min exactly associative ->
//      bit-exact (absmax stays 0.0).
//  (b) LDS DOUBLE-BUFFER: 1 barrier/tile instead of 2 (barrier i+1 already
//      separates h-read(i) from v-write(i+2)). Per-W strides keep dbuf at
//      <= 18.7 KB -> still 8 blocks/CU (149.5 KB <= 160 KB).
//  (c) full-window v-pass preload for W<=8 (16/24 loads in flight, deeper
//      MLP under the 64-VGPR cap of __launch_bounds__(256,8)).
// Equal-work blocks (NT={8,4,2,1} tiles for W={4,8,16,32}), 1920-block grid,
// single residency round — kept from R7.

#define HH 256
#define WW 256
#define BC 32
#define NS 4
#define HW (HH * WW)
#define SLICE ((long)BC * HW)

// LDS row stride per scale: 2W + 256 + 4 (multiple of 4 floats -> 16B rows)
template <int W> struct LdsStride { static constexpr int v = 2 * W + 256 + 4; };
// double buffer for NT>1 scales, single for W=32; max = 2*8*292 floats
#define LBUF_FLOATS (2 * 8 * 292)

// ---- horizontal pass over one padded LDS row; thread computes 8 outputs ----
// lw = row base + 8*t (16B-aligned); element o in [0, 2W+8) maps to d = o-W-pp
template <int W, bool IS_MAX>
__device__ __forceinline__ void hpass_lds(const float* __restrict__ lw, float cw,
                                          float acc[8])
{
    const float PAD = IS_MAX ? -1e30f : 1e30f;
#pragma unroll
    for (int pp = 0; pp < 8; ++pp) acc[pp] = PAD;
#pragma unroll
    for (int u = 0; u < (8 + 2 * W) / 4; ++u) {
        const float4 vv = *(const float4*)(lw + 4 * u);
        const float vs[4] = {vv.x, vv.y, vv.z, vv.w};
#pragma unroll
        for (int pp = 0; pp < 8; ++pp) {
#pragma unroll
            for (int e = 0; e < 4; e += 2) {            // paired -> v_max3
                const int d1 = 4 * u + e - W - pp;      // compile-time
                const int d2 = d1 + 1;
                const bool ok1 = (d1 >= -W) && (d1 <= W);
                const bool ok2 = (d2 >= -W) && (d2 <= W);
                const float K1 = (float)(d1 * d1);
                const float K2 = (float)(d2 * d2);
                if (ok1 && ok2) {
                    const float c1 = IS_MAX ? fmaf(cw, -K1, vs[e])
                                            : fmaf(cw,  K1, vs[e]);
                    const float c2 = IS_MAX ? fmaf(cw, -K2, vs[e + 1])
                                            : fmaf(cw,  K2, vs[e + 1]);
                    acc[pp] = IS_MAX ? fmaxf(acc[pp], fmaxf(c1, c2))
                                     : fminf(acc[pp], fminf(c1, c2));
                } else if (ok1) {
                    const float c1 = IS_MAX ? fmaf(cw, -K1, vs[e])
                                            : fmaf(cw,  K1, vs[e]);
                    acc[pp] = IS_MAX ? fmaxf(acc[pp], c1) : fminf(acc[pp], c1);
                } else if (ok2) {
                    const float c2 = IS_MAX ? fmaf(cw, -K2, vs[e + 1])
                                            : fmaf(cw,  K2, vs[e + 1]);
                    acc[pp] = IS_MAX ? fmaxf(acc[pp], c2) : fminf(acc[pp], c2);
                }
            }
        }
    }
}

// ---- vertical pass; thread = one column, 8 consecutive output rows ----
// CLAMP=false: caller guarantees rows [h0-W, h0+7+W] are all in-bounds.
// W<=8: whole (8+2W)-row window preloaded in one batch (deeper MLP).
template <int W, bool IS_MAX, bool CLAMP>
__device__ __forceinline__ void vpass_core(const float* __restrict__ img, int x,
                                           int h0, float cw, float acc[8])
{
    const float PAD = IS_MAX ? -1e30f : 1e30f;
    constexpr int TOT = 8 + 2 * W;
    constexpr int CH = (W <= 8) ? TOT : 8;              // chunk size (even)
#pragma unroll
    for (int pp = 0; pp < 8; ++pp) acc[pp] = PAD;
#pragma unroll
    for (int ch = 0; ch < TOT / CH; ++ch) {
        float v[CH];
#pragma unroll
        for (int q = 0; q < CH; ++q) {
            const int h = h0 + ch * CH + q - W;
            if (CLAMP) {                    // branchless clamped load
                const int hc = min(max(h, 0), HH - 1);
                const float tv = img[(long)hc * WW + x];
                v[q] = (h == hc) ? tv : PAD;
            } else {                        // interior: plain load
                v[q] = img[(long)h * WW + x];
            }
        }
#pragma unroll
        for (int pp = 0; pp < 8; ++pp) {
#pragma unroll
            for (int q = 0; q < CH; q += 2) {           // paired -> v_max3
                const int d1 = ch * CH + q - W - pp;    // compile-time
                const int d2 = d1 + 1;
                const bool ok1 = (d1 >= -W) && (d1 <= W);
                const bool ok2 = (d2 >= -W) && (d2 <= W);
                const float K1 = (float)(d1 * d1);
                const float K2 = (float)(d2 * d2);
                if (ok1 && ok2) {
                    const float c1 = IS_MAX ? fmaf(cw, -K1, v[q])
                                            : fmaf(cw,  K1, v[q]);
                    const float c2 = IS_MAX ? fmaf(cw, -K2, v[q + 1])
                                            : fmaf(cw,  K2, v[q + 1]);
                    acc[pp] = IS_MAX ? fmaxf(acc[pp], fmaxf(c1, c2))
                                     : fminf(acc[pp], fminf(c1, c2));
                } else if (ok1) {
                    const float c1 = IS_MAX ? fmaf(cw, -K1, v[q])
                                            : fmaf(cw,  K1, v[q]);
                    acc[pp] = IS_MAX ? fmaxf(acc[pp], c1) : fminf(acc[pp], c1);
                } else if (ok2) {
                    const float c2 = IS_MAX ? fmaf(cw, -K2, v[q + 1])
                                            : fmaf(cw,  K2, v[q + 1]);
                    acc[pp] = IS_MAX ? fmaxf(acc[pp], c2) : fminf(acc[pp], c2);
                }
            }
        }
    }
}

// ---- NT consecutive 8-row tiles per block, double-buffered LDS ----
template <int W, bool IS_MAX, int NT>
__device__ __forceinline__ void run_tiles(const float* __restrict__ ip,
                                          float* __restrict__ op,
                                          int y0, float c, float* lbuf)
{
    constexpr int LS = LdsStride<W>::v;
    const float cw = c * (4.0f / (float)(W * W));
    const float PAD = IS_MAX ? -1e30f : 1e30f;
    const int x = threadIdx.x;
    const int r = threadIdx.x >> 5, t = threadIdx.x & 31;

#pragma unroll 1
    for (int i = 0; i < NT; ++i) {
        float* buf = lbuf + (i & 1) * 8 * LS;           // dbuf: no trailing barrier
        const int h0 = (y0 + i) * 8;

        // phase 1: vertical pass for 8 rows (thread-per-column)
        float vacc[8];
        if (h0 >= W && h0 + 8 + W <= HH)                // block-uniform branch
            vpass_core<W, IS_MAX, false>(ip, x, h0, cw, vacc);
        else
            vpass_core<W, IS_MAX, true >(ip, x, h0, cw, vacc);

        // stash as padded LDS rows
#pragma unroll
        for (int q = 0; q < 8; ++q) buf[q * LS + W + x] = vacc[q];
        if (x < W) {
#pragma unroll
            for (int q = 0; q < 8; ++q) {
                buf[q * LS + x] = PAD;
                buf[q * LS + W + 256 + x] = PAD;
            }
        }
        __syncthreads();                                // the only barrier per tile

        // phase 2: horizontal pass on the 8-row tile
        float acc[8];
        hpass_lds<W, IS_MAX>(buf + r * LS + 8 * t, cw, acc);
        float* o = op + (long)(h0 + r) * WW + 8 * t;
        *(float4*)(o)     = make_float4(acc[0], acc[1], acc[2], acc[3]);
        *(float4*)(o + 4) = make_float4(acc[4], acc[5], acc[6], acc[7]);
    }
}

// ---- kernel ----
// kfix < 0 : full decode, 60 equal-work blocks per z-slice:
//   r<32 -> k=3 (1 tile); r<48 -> k=2 (2 tiles); r<56 -> k=1 (4); else k=0 (8)
// kfix >= 0: single-scale mode, bpz blocks per z, z = zbase + bid/bpz.
template <bool IS_MAX>
__global__ __launch_bounds__(256, 8) void k_vh(const float* __restrict__ in,
                                               float* __restrict__ out,
                                               const float* __restrict__ cptr,
                                               long in_ks, long in_zs,
                                               long out_ks, long out_zs,
                                               int kfix, int bpz, int zbase)
{
    __shared__ __align__(16) float lbuf[LBUF_FLOATS];
    const int bid = blockIdx.x;
    int k, y0, z;
    if (kfix < 0) {
        z = bid / 60;
        const int r = bid - z * 60;
        if (r < 32)      { k = 3; y0 = r; }
        else if (r < 48) { k = 2; y0 = (r - 32) * 2; }
        else if (r < 56) { k = 1; y0 = (r - 48) * 4; }
        else             { k = 0; y0 = (r - 56) * 8; }
    } else {
        k = kfix;
        const int zi = bid / bpz;
        const int yi = bid - zi * bpz;
        z = zbase + zi;
        y0 = yi * (32 / bpz);
    }
    const float c = cptr[0];
    const float* ip = in + (long)k * in_ks + (long)z * in_zs;
    float* op = out + (long)k * out_ks + (long)z * out_zs;
    switch (k) {
        case 0: run_tiles<4,  IS_MAX, 8>(ip, op, y0, c, lbuf); break;
        case 1: run_tiles<8,  IS_MAX, 4>(ip, op, y0, c, lbuf); break;
        case 2: run_tiles<16, IS_MAX, 2>(ip, op, y0, c, lbuf); break;
        case 3: run_tiles<32, IS_MAX, 1>(ip, op, y0, c, lbuf); break;
    }
}

extern "C" void kernel_launch(void* const* d_in, const int* in_sizes, int n_in,
                              void* d_out, int out_size, void* d_ws, size_t ws_size,
                              hipStream_t stream)
{
    const float* x = (const float*)d_in[0];   // [4,8,256,256] fp32
    const float* c = (const float*)d_in[1];   // scalar se_coef
    float* out = (float*)d_out;               // [4,8,4,256,256] fp32
    float* ws  = (float*)d_ws;

    dim3 b(256);
    const size_t slice_b = (size_t)SLICE * sizeof(float);        // 8.4 MB
    if (ws_size >= (size_t)NS * slice_b) {
        // main path: 2 dispatches, 60 equal-work blocks per z => 1920 blocks
        dim3 g(60 * BC);
        // K_dil: ws[k,z] = dh(dv(x[z]))   (x shared across scales: in_ks = 0)
        k_vh<true ><<<g, b, 0, stream>>>(x,  ws,  c, 0,     HW, SLICE, HW,
                                         -1, 0, 0);
        // K_ero: out[z,k] = eh(ev(ws[k,z]))
        k_vh<false><<<g, b, 0, stream>>>(ws, out, c, SLICE, HW, HW, (long)NS * HW,
                                         -1, 0, 0);
    } else if (ws_size >= slice_b) {
        // per-scale fallback: one 8.4 MB ws slice reused across scales
        for (int k = 0; k < NS; ++k) {
            const int bpz = 4 << k;                 // blocks per z-slice
            dim3 g(bpz * BC);
            k_vh<true ><<<g, b, 0, stream>>>(x,  ws,  c, 0, HW, 0, HW,
                                             k, bpz, 0);
            k_vh<false><<<g, b, 0, stream>>>(ws, out, c, 0, HW, HW, (long)NS * HW,
                                             k, bpz, 0);
        }
    } else {
        // emergency fallback: one 256 KB ws tile per (scale, z) pair
        for (int k = 0; k < NS; ++k) {
            const int bpz = 4 << k;
            dim3 g(bpz);
            for (int z = 0; z < BC; ++z) {
                k_vh<true ><<<g, b, 0, stream>>>(x,  ws,  c, 0, HW, 0, 0,
                                                 k, bpz, z);
                k_vh<false><<<g, b, 0, stream>>>(ws, out, c, 0, 0, HW, (long)NS * HW,
                                                 k, bpz, z);
            }
        }
    }
}

// Round 5
// 121.871 us; speedup vs baseline: 1.0556x; 1.0556x over previous
//
#include <hip/hip_runtime.h>

// Multi-scale parabolic morphological closing, 2-dispatch fused pipeline.
// Algebra: dilations along different axes commute (max-plus), as do erosions:
//   closing = ev.eh.dv.dh = (eh.ev).(dh.dv)
//   K_dil: ws  = dh(dv(x))      (both max)
//   K_ero: out = eh(ev(ws))     (both min)
// weight(d) = c * (4/W^2) * d^2 — pow2 * small-int products are exact.
//
// R9 (unbundling R8's regression 119.8 -> 128.6): R8 bundled (a) tap pairing
// -> v_max3, (b) LDS double-buffer / 1 barrier per tile, (c) full-window
// v-pass preload for W<=8. Fault model: (c) kept v[24]+acc[8]+clamp temps
// live under the 64-VGPR cap of __launch_bounds__(256,8) -> scratch spill.
// R9 = R7's measured-good CH=8 chunked v-pass loads + (a) + (b) only.
//   - pairing: acc = op(acc, op(c1,c2)) fuses to v_max3/v_min3: 3 VALU per
//     2 taps (-25%); max/min exactly associative -> bit-exact.
//   - dbuf: barrier i+1 already orders h-read(i) before v-write(i+2);
//     18.7 KB * 8 blocks = 149.5 KB <= 160 KB keeps 8 blocks/CU.
// Equal-work blocks (NT={8,4,2,1} tiles for W={4,8,16,32}), 1920-block grid,
// single residency round — kept from R7.

#define HH 256
#define WW 256
#define BC 32
#define NS 4
#define HW (HH * WW)
#define SLICE ((long)BC * HW)

// LDS row stride per scale: 2W + 256 + 4 (multiple of 4 floats -> 16B rows)
template <int W> struct LdsStride { static constexpr int v = 2 * W + 256 + 4; };
// double buffer sized for the largest NT>1 scale (W=16: 292); W=32 (324) is
// single-tile and uses the buffer un-doubled.
#define LBUF_FLOATS (2 * 8 * 292)

// ---- horizontal pass over one padded LDS row; thread computes 8 outputs ----
// lw = row base + 8*t (16B-aligned); element o in [0, 2W+8) maps to d = o-W-pp
template <int W, bool IS_MAX>
__device__ __forceinline__ void hpass_lds(const float* __restrict__ lw, float cw,
                                          float acc[8])
{
    const float PAD = IS_MAX ? -1e30f : 1e30f;
#pragma unroll
    for (int pp = 0; pp < 8; ++pp) acc[pp] = PAD;
#pragma unroll
    for (int u = 0; u < (8 + 2 * W) / 4; ++u) {
        const float4 vv = *(const float4*)(lw + 4 * u);
        const float vs[4] = {vv.x, vv.y, vv.z, vv.w};
#pragma unroll
        for (int pp = 0; pp < 8; ++pp) {
#pragma unroll
            for (int e = 0; e < 4; e += 2) {            // paired -> v_max3
                const int d1 = 4 * u + e - W - pp;      // compile-time
                const int d2 = d1 + 1;
                const bool ok1 = (d1 >= -W) && (d1 <= W);
                const bool ok2 = (d2 >= -W) && (d2 <= W);
                const float K1 = (float)(d1 * d1);
                const float K2 = (float)(d2 * d2);
                if (ok1 && ok2) {
                    const float c1 = IS_MAX ? fmaf(cw, -K1, vs[e])
                                            : fmaf(cw,  K1, vs[e]);
                    const float c2 = IS_MAX ? fmaf(cw, -K2, vs[e + 1])
                                            : fmaf(cw,  K2, vs[e + 1]);
                    acc[pp] = IS_MAX ? fmaxf(acc[pp], fmaxf(c1, c2))
                                     : fminf(acc[pp], fminf(c1, c2));
                } else if (ok1) {
                    const float c1 = IS_MAX ? fmaf(cw, -K1, vs[e])
                                            : fmaf(cw,  K1, vs[e]);
                    acc[pp] = IS_MAX ? fmaxf(acc[pp], c1) : fminf(acc[pp], c1);
                } else if (ok2) {
                    const float c2 = IS_MAX ? fmaf(cw, -K2, vs[e + 1])
                                            : fmaf(cw,  K2, vs[e + 1]);
                    acc[pp] = IS_MAX ? fmaxf(acc[pp], c2) : fminf(acc[pp], c2);
                }
            }
        }
    }
}

// ---- vertical pass; thread = one column, 8 consecutive output rows ----
// CLAMP=false: caller guarantees rows [h0-W, h0+7+W] are all in-bounds.
// Chunked 8-row loads (R7-proven; full-window preload spilled under the
// 64-VGPR cap — R8 regression).
template <int W, bool IS_MAX, bool CLAMP>
__device__ __forceinline__ void vpass_core(const float* __restrict__ img, int x,
                                           int h0, float cw, float acc[8])
{
    const float PAD = IS_MAX ? -1e30f : 1e30f;
    constexpr int TOT = 8 + 2 * W;
#pragma unroll
    for (int pp = 0; pp < 8; ++pp) acc[pp] = PAD;
#pragma unroll
    for (int ch = 0; ch < TOT / 8; ++ch) {
        float v[8];
#pragma unroll
        for (int q = 0; q < 8; ++q) {
            const int h = h0 + ch * 8 + q - W;
            if (CLAMP) {                    // branchless clamped load
                const int hc = min(max(h, 0), HH - 1);
                const float tv = img[(long)hc * WW + x];
                v[q] = (h == hc) ? tv : PAD;
            } else {                        // interior: plain load
                v[q] = img[(long)h * WW + x];
            }
        }
#pragma unroll
        for (int pp = 0; pp < 8; ++pp) {
#pragma unroll
            for (int q = 0; q < 8; q += 2) {            // paired -> v_max3
                const int d1 = ch * 8 + q - W - pp;     // compile-time
                const int d2 = d1 + 1;
                const bool ok1 = (d1 >= -W) && (d1 <= W);
                const bool ok2 = (d2 >= -W) && (d2 <= W);
                const float K1 = (float)(d1 * d1);
                const float K2 = (float)(d2 * d2);
                if (ok1 && ok2) {
                    const float c1 = IS_MAX ? fmaf(cw, -K1, v[q])
                                            : fmaf(cw,  K1, v[q]);
                    const float c2 = IS_MAX ? fmaf(cw, -K2, v[q + 1])
                                            : fmaf(cw,  K2, v[q + 1]);
                    acc[pp] = IS_MAX ? fmaxf(acc[pp], fmaxf(c1, c2))
                                     : fminf(acc[pp], fminf(c1, c2));
                } else if (ok1) {
                    const float c1 = IS_MAX ? fmaf(cw, -K1, v[q])
                                            : fmaf(cw,  K1, v[q]);
                    acc[pp] = IS_MAX ? fmaxf(acc[pp], c1) : fminf(acc[pp], c1);
                } else if (ok2) {
                    const float c2 = IS_MAX ? fmaf(cw, -K2, v[q + 1])
                                            : fmaf(cw,  K2, v[q + 1]);
                    acc[pp] = IS_MAX ? fmaxf(acc[pp], c2) : fminf(acc[pp], c2);
                }
            }
        }
    }
}

// ---- NT consecutive 8-row tiles per block, double-buffered LDS ----
template <int W, bool IS_MAX, int NT>
__device__ __forceinline__ void run_tiles(const float* __restrict__ ip,
                                          float* __restrict__ op,
                                          int y0, float c, float* lbuf)
{
    constexpr int LS = LdsStride<W>::v;
    const float cw = c * (4.0f / (float)(W * W));
    const float PAD = IS_MAX ? -1e30f : 1e30f;
    const int x = threadIdx.x;
    const int r = threadIdx.x >> 5, t = threadIdx.x & 31;

#pragma unroll 1
    for (int i = 0; i < NT; ++i) {
        float* buf = lbuf + (i & 1) * 8 * LS;           // dbuf: no trailing barrier
        const int h0 = (y0 + i) * 8;

        // phase 1: vertical pass for 8 rows (thread-per-column)
        float vacc[8];
        if (h0 >= W && h0 + 8 + W <= HH)                // block-uniform branch
            vpass_core<W, IS_MAX, false>(ip, x, h0, cw, vacc);
        else
            vpass_core<W, IS_MAX, true >(ip, x, h0, cw, vacc);

        // stash as padded LDS rows
#pragma unroll
        for (int q = 0; q < 8; ++q) buf[q * LS + W + x] = vacc[q];
        if (x < W) {
#pragma unroll
            for (int q = 0; q < 8; ++q) {
                buf[q * LS + x] = PAD;
                buf[q * LS + W + 256 + x] = PAD;
            }
        }
        __syncthreads();                                // the only barrier per tile

        // phase 2: horizontal pass on the 8-row tile
        float acc[8];
        hpass_lds<W, IS_MAX>(buf + r * LS + 8 * t, cw, acc);
        float* o = op + (long)(h0 + r) * WW + 8 * t;
        *(float4*)(o)     = make_float4(acc[0], acc[1], acc[2], acc[3]);
        *(float4*)(o + 4) = make_float4(acc[4], acc[5], acc[6], acc[7]);
    }
}

// ---- kernel ----
// kfix < 0 : full decode, 60 equal-work blocks per z-slice:
//   r<32 -> k=3 (1 tile); r<48 -> k=2 (2 tiles); r<56 -> k=1 (4); else k=0 (8)
// kfix >= 0: single-scale mode, bpz blocks per z, z = zbase + bid/bpz.
template <bool IS_MAX>
__global__ __launch_bounds__(256, 8) void k_vh(const float* __restrict__ in,
                                               float* __restrict__ out,
                                               const float* __restrict__ cptr,
                                               long in_ks, long in_zs,
                                               long out_ks, long out_zs,
                                               int kfix, int bpz, int zbase)
{
    __shared__ __align__(16) float lbuf[LBUF_FLOATS];
    const int bid = blockIdx.x;
    int k, y0, z;
    if (kfix < 0) {
        z = bid / 60;
        const int r = bid - z * 60;
        if (r < 32)      { k = 3; y0 = r; }
        else if (r < 48) { k = 2; y0 = (r - 32) * 2; }
        else if (r < 56) { k = 1; y0 = (r - 48) * 4; }
        else             { k = 0; y0 = (r - 56) * 8; }
    } else {
        k = kfix;
        const int zi = bid / bpz;
        const int yi = bid - zi * bpz;
        z = zbase + zi;
        y0 = yi * (32 / bpz);
    }
    const float c = cptr[0];
    const float* ip = in + (long)k * in_ks + (long)z * in_zs;
    float* op = out + (long)k * out_ks + (long)z * out_zs;
    switch (k) {
        case 0: run_tiles<4,  IS_MAX, 8>(ip, op, y0, c, lbuf); break;
        case 1: run_tiles<8,  IS_MAX, 4>(ip, op, y0, c, lbuf); break;
        case 2: run_tiles<16, IS_MAX, 2>(ip, op, y0, c, lbuf); break;
        case 3: run_tiles<32, IS_MAX, 1>(ip, op, y0, c, lbuf); break;
    }
}

extern "C" void kernel_launch(void* const* d_in, const int* in_sizes, int n_in,
                              void* d_out, int out_size, void* d_ws, size_t ws_size,
                              hipStream_t stream)
{
    const float* x = (const float*)d_in[0];   // [4,8,256,256] fp32
    const float* c = (const float*)d_in[1];   // scalar se_coef
    float* out = (float*)d_out;               // [4,8,4,256,256] fp32
    float* ws  = (float*)d_ws;

    dim3 b(256);
    const size_t slice_b = (size_t)SLICE * sizeof(float);        // 8.4 MB
    if (ws_size >= (size_t)NS * slice_b) {
        // main path: 2 dispatches, 60 equal-work blocks per z => 1920 blocks
        dim3 g(60 * BC);
        // K_dil: ws[k,z] = dh(dv(x[z]))   (x shared across scales: in_ks = 0)
        k_vh<true ><<<g, b, 0, stream>>>(x,  ws,  c, 0,     HW, SLICE, HW,
                                         -1, 0, 0);
        // K_ero: out[z,k] = eh(ev(ws[k,z]))
        k_vh<false><<<g, b, 0, stream>>>(ws, out, c, SLICE, HW, HW, (long)NS * HW,
                                         -1, 0, 0);
    } else if (ws_size >= slice_b) {
        // per-scale fallback: one 8.4 MB ws slice reused across scales
        for (int k = 0; k < NS; ++k) {
            const int bpz = 4 << k;                 // blocks per z-slice
            dim3 g(bpz * BC);
            k_vh<true ><<<g, b, 0, stream>>>(x,  ws,  c, 0, HW, 0, HW,
                                             k, bpz, 0);
            k_vh<false><<<g, b, 0, stream>>>(ws, out, c, 0, HW, HW, (long)NS * HW,
                                             k, bpz, 0);
        }
    } else {
        // emergency fallback: one 256 KB ws tile per (scale, z) pair
        for (int k = 0; k < NS; ++k) {
            const int bpz = 4 << k;
            dim3 g(bpz);
            for (int z = 0; z < BC; ++z) {
                k_vh<true ><<<g, b, 0, stream>>>(x,  ws,  c, 0, HW, 0, 0,
                                                 k, bpz, z);
                k_vh<false><<<g, b, 0, stream>>>(ws, out, c, 0, 0, HW, (long)NS * HW,
                                                 k, bpz, z);
            }
        }
    }
}

// Round 6
// 121.450 us; speedup vs baseline: 1.0593x; 1.0035x over previous
//
#include <hip/hip_runtime.h>

// Multi-scale parabolic morphological closing, 2-dispatch fused pipeline.
// Algebra: dilations along different axes commute (max-plus), as do erosions:
//   closing = ev.eh.dv.dh = (eh.ev).(dh.dv)
//   K_dil: ws  = dh(dv(x))      (both max)
//   K_ero: out = eh(ev(ws))     (both min)
// weight(d) = c * (4/W^2) * d^2 — pow2 * small-int products are exact.
//
// R10 (from R9 post-mortem): pairing/dbuf neutral (clang already emits v_max3;
// 8 blocks/CU already hides barriers). Tap-issue floor is only ~10us/kernel vs
// 36us measured, VALUBusy ~45% -> the dominant stall is hypothesized to be
// INSTRUCTION-CACHE THRASH: the unrolled 4-scale switch is ~40KB of code and
// scale-interleaved residency puts all variants on every CU vs 32KB I$.
// Fix under test (single variable): SCALE-CLUSTERED CU MAPPING. Dispatch is
// round-robin across XCDs (bid%8) and CUs (bid/8%32) -> CU ~ bid%256 when the
// grid is fully resident. k = f(bid&255):
//   rid [0,128) -> W=32 (NT=1), [128,192) -> W=16 (NT=2),
//   [192,224) -> W=8 (NT=4), [224,240) -> W=4 (NT=8), [240,256) idle.
// 2048 blocks x 8 slots/residue; each CU runs ONE W-variant (fits I$);
// per-CU work 520/528/544/576 units (+11% worst); 16 CUs idle (6%).
// If theory true: ~105-110us; if false: ~122-126 -> falsified, move on.

#define HH 256
#define WW 256
#define BC 32
#define NS 4
#define HW (HH * WW)
#define SLICE ((long)BC * HW)

// LDS row stride per scale: 2W + 256 + 4 (multiple of 4 floats -> 16B rows)
template <int W> struct LdsStride { static constexpr int v = 2 * W + 256 + 4; };
// double buffer sized for the largest NT>1 scale (W=16: 292); W=32 (324) is
// single-tile and uses the buffer un-doubled.
#define LBUF_FLOATS (2 * 8 * 292)

// ---- horizontal pass over one padded LDS row; thread computes 8 outputs ----
// lw = row base + 8*t (16B-aligned); element o in [0, 2W+8) maps to d = o-W-pp
template <int W, bool IS_MAX>
__device__ __forceinline__ void hpass_lds(const float* __restrict__ lw, float cw,
                                          float acc[8])
{
    const float PAD = IS_MAX ? -1e30f : 1e30f;
#pragma unroll
    for (int pp = 0; pp < 8; ++pp) acc[pp] = PAD;
#pragma unroll
    for (int u = 0; u < (8 + 2 * W) / 4; ++u) {
        const float4 vv = *(const float4*)(lw + 4 * u);
        const float vs[4] = {vv.x, vv.y, vv.z, vv.w};
#pragma unroll
        for (int pp = 0; pp < 8; ++pp) {
#pragma unroll
            for (int e = 0; e < 4; e += 2) {            // paired -> v_max3
                const int d1 = 4 * u + e - W - pp;      // compile-time
                const int d2 = d1 + 1;
                const bool ok1 = (d1 >= -W) && (d1 <= W);
                const bool ok2 = (d2 >= -W) && (d2 <= W);
                const float K1 = (float)(d1 * d1);
                const float K2 = (float)(d2 * d2);
                if (ok1 && ok2) {
                    const float c1 = IS_MAX ? fmaf(cw, -K1, vs[e])
                                            : fmaf(cw,  K1, vs[e]);
                    const float c2 = IS_MAX ? fmaf(cw, -K2, vs[e + 1])
                                            : fmaf(cw,  K2, vs[e + 1]);
                    acc[pp] = IS_MAX ? fmaxf(acc[pp], fmaxf(c1, c2))
                                     : fminf(acc[pp], fminf(c1, c2));
                } else if (ok1) {
                    const float c1 = IS_MAX ? fmaf(cw, -K1, vs[e])
                                            : fmaf(cw,  K1, vs[e]);
                    acc[pp] = IS_MAX ? fmaxf(acc[pp], c1) : fminf(acc[pp], c1);
                } else if (ok2) {
                    const float c2 = IS_MAX ? fmaf(cw, -K2, vs[e + 1])
                                            : fmaf(cw,  K2, vs[e + 1]);
                    acc[pp] = IS_MAX ? fmaxf(acc[pp], c2) : fminf(acc[pp], c2);
                }
            }
        }
    }
}

// ---- vertical pass; thread = one column, 8 consecutive output rows ----
// CLAMP=false: caller guarantees rows [h0-W, h0+7+W] are all in-bounds.
// Chunked 8-row loads (R7-proven; full preload spilled under 64-VGPR cap).
template <int W, bool IS_MAX, bool CLAMP>
__device__ __forceinline__ void vpass_core(const float* __restrict__ img, int x,
                                           int h0, float cw, float acc[8])
{
    const float PAD = IS_MAX ? -1e30f : 1e30f;
    constexpr int TOT = 8 + 2 * W;
#pragma unroll
    for (int pp = 0; pp < 8; ++pp) acc[pp] = PAD;
#pragma unroll
    for (int ch = 0; ch < TOT / 8; ++ch) {
        float v[8];
#pragma unroll
        for (int q = 0; q < 8; ++q) {
            const int h = h0 + ch * 8 + q - W;
            if (CLAMP) {                    // branchless clamped load
                const int hc = min(max(h, 0), HH - 1);
                const float tv = img[(long)hc * WW + x];
                v[q] = (h == hc) ? tv : PAD;
            } else {                        // interior: plain load
                v[q] = img[(long)h * WW + x];
            }
        }
#pragma unroll
        for (int pp = 0; pp < 8; ++pp) {
#pragma unroll
            for (int q = 0; q < 8; q += 2) {            // paired -> v_max3
                const int d1 = ch * 8 + q - W - pp;     // compile-time
                const int d2 = d1 + 1;
                const bool ok1 = (d1 >= -W) && (d1 <= W);
                const bool ok2 = (d2 >= -W) && (d2 <= W);
                const float K1 = (float)(d1 * d1);
                const float K2 = (float)(d2 * d2);
                if (ok1 && ok2) {
                    const float c1 = IS_MAX ? fmaf(cw, -K1, v[q])
                                            : fmaf(cw,  K1, v[q]);
                    const float c2 = IS_MAX ? fmaf(cw, -K2, v[q + 1])
                                            : fmaf(cw,  K2, v[q + 1]);
                    acc[pp] = IS_MAX ? fmaxf(acc[pp], fmaxf(c1, c2))
                                     : fminf(acc[pp], fminf(c1, c2));
                } else if (ok1) {
                    const float c1 = IS_MAX ? fmaf(cw, -K1, v[q])
                                            : fmaf(cw,  K1, v[q]);
                    acc[pp] = IS_MAX ? fmaxf(acc[pp], c1) : fminf(acc[pp], c1);
                } else if (ok2) {
                    const float c2 = IS_MAX ? fmaf(cw, -K2, v[q + 1])
                                            : fmaf(cw,  K2, v[q + 1]);
                    acc[pp] = IS_MAX ? fmaxf(acc[pp], c2) : fminf(acc[pp], c2);
                }
            }
        }
    }
}

// ---- NT consecutive 8-row tiles per block, double-buffered LDS ----
template <int W, bool IS_MAX, int NT>
__device__ __forceinline__ void run_tiles(const float* __restrict__ ip,
                                          float* __restrict__ op,
                                          int y0, float c, float* lbuf)
{
    constexpr int LS = LdsStride<W>::v;
    const float cw = c * (4.0f / (float)(W * W));
    const float PAD = IS_MAX ? -1e30f : 1e30f;
    const int x = threadIdx.x;
    const int r = threadIdx.x >> 5, t = threadIdx.x & 31;

#pragma unroll 1
    for (int i = 0; i < NT; ++i) {
        float* buf = lbuf + (i & 1) * 8 * LS;           // dbuf: no trailing barrier
        const int h0 = (y0 + i) * 8;

        // phase 1: vertical pass for 8 rows (thread-per-column)
        float vacc[8];
        if (h0 >= W && h0 + 8 + W <= HH)                // block-uniform branch
            vpass_core<W, IS_MAX, false>(ip, x, h0, cw, vacc);
        else
            vpass_core<W, IS_MAX, true >(ip, x, h0, cw, vacc);

        // stash as padded LDS rows
#pragma unroll
        for (int q = 0; q < 8; ++q) buf[q * LS + W + x] = vacc[q];
        if (x < W) {
#pragma unroll
            for (int q = 0; q < 8; ++q) {
                buf[q * LS + x] = PAD;
                buf[q * LS + W + 256 + x] = PAD;
            }
        }
        __syncthreads();                                // the only barrier per tile

        // phase 2: horizontal pass on the 8-row tile
        float acc[8];
        hpass_lds<W, IS_MAX>(buf + r * LS + 8 * t, cw, acc);
        float* o = op + (long)(h0 + r) * WW + 8 * t;
        *(float4*)(o)     = make_float4(acc[0], acc[1], acc[2], acc[3]);
        *(float4*)(o + 4) = make_float4(acc[4], acc[5], acc[6], acc[7]);
    }
}

// ---- kernel ----
// kfix < 0 : scale-clustered decode over 2048 blocks (see header comment):
//   rid = bid&255 selects the scale (CU-resident under round-robin dispatch),
//   slot = bid>>8 in [0,8) selects which of the residue's 8 tile-groups.
// kfix >= 0: single-scale mode, bpz blocks per z, z = zbase + bid/bpz.
template <bool IS_MAX>
__global__ __launch_bounds__(256, 8) void k_vh(const float* __restrict__ in,
                                               float* __restrict__ out,
                                               const float* __restrict__ cptr,
                                               long in_ks, long in_zs,
                                               long out_ks, long out_zs,
                                               int kfix, int bpz, int zbase)
{
    __shared__ __align__(16) float lbuf[LBUF_FLOATS];
    const int bid = blockIdx.x;
    int k, y0, z;
    if (kfix < 0) {
        const int rid  = bid & 255;
        const int slot = bid >> 8;                      // 0..7
        int idx;
        if (rid < 128)      { k = 3; idx = rid * 8 + slot;
                              z = idx >> 5; y0 = idx & 31; }          // 1024 tiles
        else if (rid < 192) { k = 2; idx = (rid - 128) * 8 + slot;
                              z = idx >> 4; y0 = (idx & 15) * 2; }    // 512 blocks
        else if (rid < 224) { k = 1; idx = (rid - 192) * 8 + slot;
                              z = idx >> 3; y0 = (idx & 7) * 4; }     // 256 blocks
        else if (rid < 240) { k = 0; idx = (rid - 224) * 8 + slot;
                              z = idx >> 2; y0 = (idx & 3) * 8; }     // 128 blocks
        else return;                                    // 16 idle residues
    } else {
        k = kfix;
        const int zi = bid / bpz;
        const int yi = bid - zi * bpz;
        z = zbase + zi;
        y0 = yi * (32 / bpz);
    }
    const float c = cptr[0];
    const float* ip = in + (long)k * in_ks + (long)z * in_zs;
    float* op = out + (long)k * out_ks + (long)z * out_zs;
    switch (k) {
        case 0: run_tiles<4,  IS_MAX, 8>(ip, op, y0, c, lbuf); break;
        case 1: run_tiles<8,  IS_MAX, 4>(ip, op, y0, c, lbuf); break;
        case 2: run_tiles<16, IS_MAX, 2>(ip, op, y0, c, lbuf); break;
        case 3: run_tiles<32, IS_MAX, 1>(ip, op, y0, c, lbuf); break;
    }
}

extern "C" void kernel_launch(void* const* d_in, const int* in_sizes, int n_in,
                              void* d_out, int out_size, void* d_ws, size_t ws_size,
                              hipStream_t stream)
{
    const float* x = (const float*)d_in[0];   // [4,8,256,256] fp32
    const float* c = (const float*)d_in[1];   // scalar se_coef
    float* out = (float*)d_out;               // [4,8,4,256,256] fp32
    float* ws  = (float*)d_ws;

    dim3 b(256);
    const size_t slice_b = (size_t)SLICE * sizeof(float);        // 8.4 MB
    if (ws_size >= (size_t)NS * slice_b) {
        // main path: 2 dispatches, scale-clustered 2048-block grid
        dim3 g(2048);
        // K_dil: ws[k,z] = dh(dv(x[z]))   (x shared across scales: in_ks = 0)
        k_vh<true ><<<g, b, 0, stream>>>(x,  ws,  c, 0,     HW, SLICE, HW,
                                         -1, 0, 0);
        // K_ero: out[z,k] = eh(ev(ws[k,z]))
        k_vh<false><<<g, b, 0, stream>>>(ws, out, c, SLICE, HW, HW, (long)NS * HW,
                                         -1, 0, 0);
    } else if (ws_size >= slice_b) {
        // per-scale fallback: one 8.4 MB ws slice reused across scales
        for (int k = 0; k < NS; ++k) {
            const int bpz = 4 << k;                 // blocks per z-slice
            dim3 g(bpz * BC);
            k_vh<true ><<<g, b, 0, stream>>>(x,  ws,  c, 0, HW, 0, HW,
                                             k, bpz, 0);
            k_vh<false><<<g, b, 0, stream>>>(ws, out, c, 0, HW, HW, (long)NS * HW,
                                             k, bpz, 0);
        }
    } else {
        // emergency fallback: one 256 KB ws tile per (scale, z) pair
        for (int k = 0; k < NS; ++k) {
            const int bpz = 4 << k;
            dim3 g(bpz);
            for (int z = 0; z < BC; ++z) {
                k_vh<true ><<<g, b, 0, stream>>>(x,  ws,  c, 0, HW, 0, 0,
                                                 k, bpz, z);
                k_vh<false><<<g, b, 0, stream>>>(ws, out, c, 0, 0, HW, (long)NS * HW,
                                                 k, bpz, z);
            }
        }
    }
}